// Round 2
// baseline (104.975 us; speedup 1.0000x reference)
//
#include <hip/hip_runtime.h>

typedef __attribute__((ext_vector_type(8))) short short8;
typedef __attribute__((ext_vector_type(8))) unsigned short ushort8;
typedef __attribute__((ext_vector_type(4))) unsigned short ushort4v;
typedef __attribute__((ext_vector_type(4))) int int4v;
typedef __attribute__((ext_vector_type(4))) float f32x4;

#define Mdim 64
#define Kdim 8192
#define Ndim 8192
#define GRP 128
#define NGRP 64
#define BN 32
#define PITCH 136   // 128 + 8 pad: 272B row pitch, 16B-aligned for b128

__device__ __forceinline__ unsigned short f2bf(float f) {
    unsigned int u = __builtin_bit_cast(unsigned int, f);
    u += 0x7FFFu + ((u >> 16) & 1u);   // round-to-nearest-even
    return (unsigned short)(u >> 16);
}
__device__ __forceinline__ float bf2f(unsigned short h) {
    unsigned int u = ((unsigned int)h) << 16;
    return __builtin_bit_cast(float, u);
}

// Build xh/xl (hi/lo bf16 split of x) and per-(group,m) sums xsum[g][m].
// 4096 units (m,g), 32 lanes each: lane handles 4 consecutive k.
__global__ void prep_kernel(const float* __restrict__ x,
                            unsigned short* __restrict__ xh,
                            unsigned short* __restrict__ xl,
                            float* __restrict__ xsum) {
    const int tid = threadIdx.x;
    const int u = blockIdx.x * 8 + (tid >> 5);
    const int g = u & (NGRP - 1);
    const int m = u >> 6;
    const int lane = tid & 31;
    const int k = g * GRP + lane * 4;
    f32x4 v = *(const f32x4*)(x + (size_t)m * Kdim + k);
    ushort4v hv, lv;
    float s = 0.f;
#pragma unroll
    for (int i = 0; i < 4; ++i) {
        unsigned short h = f2bf(v[i]);
        hv[i] = h;
        lv[i] = f2bf(v[i] - bf2f(h));
        s += v[i];
    }
    *(ushort4v*)(xh + (size_t)m * Kdim + k) = hv;
    *(ushort4v*)(xl + (size_t)m * Kdim + k) = lv;
#pragma unroll
    for (int off = 16; off > 0; off >>= 1) s += __shfl_down(s, off, 32);
    if (lane == 0) xsum[g * Mdim + m] = s;
}

// Main: 256 blocks (BN=32 cols each), 512 threads = 8 waves = 4 m-tiles x 2 n-strips.
// Per stage: one K-group (128 rows) double-buffered in LDS; q converted to bf16
// during reg-staging (exact for |q|<=128); group-scale epilogue in fp32.
__launch_bounds__(512)
__global__ void qlin_kernel(const unsigned short* __restrict__ xh,
                            const unsigned short* __restrict__ xl,
                            const int* __restrict__ qw,
                            const float* __restrict__ scales,
                            const float* __restrict__ zeros,
                            const float* __restrict__ bias,
                            const float* __restrict__ xsum,
                            float* __restrict__ out) {
    __shared__ unsigned short lq[2][BN][PITCH];
    __shared__ unsigned short lxh[2][Mdim][PITCH];
    __shared__ unsigned short lxl[2][Mdim][PITCH];

    const int tid = threadIdx.x;
    const int n0 = blockIdx.x * BN;
    const int w = tid >> 6;
    const int l = tid & 63;
    const int mt = w >> 1;        // m-tile 0..3 (16 rows each)
    const int wn = w & 1;         // n-strip 0..1 (16 cols each)
    const int lcol = l & 15;
    const int lhi = l >> 4;

    // q staging coords: thread covers 2 k-rows x 4 cols
    const int qc = tid & 7;       // col quad
    const int qp = tid >> 3;      // k-pair 0..63
    // x staging coords: thread covers one (row, 8k-chunk) per array half
    const int xm0 = tid >> 4;             // 0..31
    const int xk0 = (tid & 15) * 8;       // 0..120

    int4v qa, qb;
    ushort8 ha0, ha1, la0, la1;

    auto LOADS = [&](int g) {
        const size_t k0 = (size_t)g * GRP;
        qa = __builtin_nontemporal_load((const int4v*)(qw + (k0 + 2 * qp) * Ndim + n0 + 4 * qc));
        qb = __builtin_nontemporal_load((const int4v*)(qw + (k0 + 2 * qp + 1) * Ndim + n0 + 4 * qc));
        ha0 = *(const ushort8*)(xh + (size_t)xm0 * Kdim + k0 + xk0);
        ha1 = *(const ushort8*)(xh + (size_t)(xm0 + 32) * Kdim + k0 + xk0);
        la0 = *(const ushort8*)(xl + (size_t)xm0 * Kdim + k0 + xk0);
        la1 = *(const ushort8*)(xl + (size_t)(xm0 + 32) * Kdim + k0 + xk0);
    };
    auto WRITES = [&](int b) {
#pragma unroll
        for (int j = 0; j < 4; ++j) {
            unsigned int pk = (unsigned int)f2bf((float)qa[j]) |
                              ((unsigned int)f2bf((float)qb[j]) << 16);
            *(unsigned int*)&lq[b][4 * qc + j][2 * qp] = pk;
        }
        *(ushort8*)&lxh[b][xm0][xk0] = ha0;
        *(ushort8*)&lxh[b][xm0 + 32][xk0] = ha1;
        *(ushort8*)&lxl[b][xm0][xk0] = la0;
        *(ushort8*)&lxl[b][xm0 + 32][xk0] = la1;
    };

    f32x4 acc = {0.f, 0.f, 0.f, 0.f};
    f32x4 p = {0.f, 0.f, 0.f, 0.f};

    LOADS(0);
    WRITES(0);
    __syncthreads();

    const int gn = n0 + wn * 16 + lcol;

    for (int g = 0; g < NGRP; ++g) {
        const int cb = g & 1;
        if (g + 1 < NGRP) LOADS(g + 1);
#pragma unroll
        for (int ks = 0; ks < 4; ++ks) {
            short8 bfrag = *(const short8*)&lq[cb][wn * 16 + lcol][ks * 32 + lhi * 8];
            short8 ah = *(const short8*)&lxh[cb][mt * 16 + lcol][ks * 32 + lhi * 8];
            short8 al = *(const short8*)&lxl[cb][mt * 16 + lcol][ks * 32 + lhi * 8];
            p = __builtin_amdgcn_mfma_f32_16x16x32_bf16(ah, bfrag, p, 0, 0, 0);
            p = __builtin_amdgcn_mfma_f32_16x16x32_bf16(al, bfrag, p, 0, 0, 0);
        }
        // group epilogue: fold exact int-sums with fp32 scale/zero correction
        float s = scales[(size_t)g * Ndim + gn];
        float z = zeros[(size_t)g * Ndim + gn];
        f32x4 xs = *(const f32x4*)(xsum + g * Mdim + mt * 16 + lhi * 4);
#pragma unroll
        for (int r = 0; r < 4; ++r) {
            acc[r] += s * (p[r] - z * xs[r]);
            p[r] = 0.f;
        }
        if (g + 1 < NGRP) WRITES(cb ^ 1);
        __syncthreads();
    }

    const float bv = bias[gn];
#pragma unroll
    for (int r = 0; r < 4; ++r) {
        out[(size_t)(mt * 16 + lhi * 4 + r) * Ndim + gn] = acc[r] + bv;
    }
}

extern "C" void kernel_launch(void* const* d_in, const int* in_sizes, int n_in,
                              void* d_out, int out_size, void* d_ws, size_t ws_size,
                              hipStream_t stream) {
    const float* x = (const float*)d_in[0];
    const int* qw = (const int*)d_in[1];
    const float* scales = (const float*)d_in[2];
    const float* zeros = (const float*)d_in[3];
    const float* bias = (const float*)d_in[4];
    // d_in[5] = group_size (==128, baked in)

    unsigned short* xh = (unsigned short*)d_ws;
    unsigned short* xl = xh + (size_t)Mdim * Kdim;
    float* xsum = (float*)(xl + (size_t)Mdim * Kdim);
    float* out = (float*)d_out;

    prep_kernel<<<512, 256, 0, stream>>>(x, xh, xl, xsum);
    qlin_kernel<<<Ndim / BN, 512, 0, stream>>>(xh, xl, qw, scales, zeros, bias, xsum, out);
}

// Round 3
// 90.830 us; speedup vs baseline: 1.1557x; 1.1557x over previous
//
#include <hip/hip_runtime.h>

typedef __attribute__((ext_vector_type(8))) short short8;
typedef __attribute__((ext_vector_type(8))) unsigned short ushort8;
typedef __attribute__((ext_vector_type(4))) unsigned short ushort4v;
typedef __attribute__((ext_vector_type(4))) int int4v;
typedef __attribute__((ext_vector_type(4))) float f32x4;

#define Mdim 64
#define Kdim 8192
#define Ndim 8192
#define GRP 128
#define NGRP 64
#define KSPLIT 2
#define NG2 (NGRP / KSPLIT)   // groups per block
#define BN 32
#define PITCH 136   // 128 + 8 pad: 272B row pitch, 16B-aligned, 2-way-free bank stride

__device__ __forceinline__ unsigned short f2bf(float f) {
    unsigned int u = __builtin_bit_cast(unsigned int, f);
    u += 0x7FFFu + ((u >> 16) & 1u);   // round-to-nearest-even
    return (unsigned short)(u >> 16);
}
__device__ __forceinline__ float bf2f(unsigned short h) {
    unsigned int u = ((unsigned int)h) << 16;
    return __builtin_bit_cast(float, u);
}

// Build xh/xl (hi/lo bf16 split of x) and per-(group,m) sums xsum[g][m].
__global__ void prep_kernel(const float* __restrict__ x,
                            unsigned short* __restrict__ xh,
                            unsigned short* __restrict__ xl,
                            float* __restrict__ xsum) {
    const int tid = threadIdx.x;
    const int u = blockIdx.x * 8 + (tid >> 5);
    const int g = u & (NGRP - 1);
    const int m = u >> 6;
    const int lane = tid & 31;
    const int k = g * GRP + lane * 4;
    f32x4 v = *(const f32x4*)(x + (size_t)m * Kdim + k);
    ushort4v hv, lv;
    float s = 0.f;
#pragma unroll
    for (int i = 0; i < 4; ++i) {
        unsigned short h = f2bf(v[i]);
        hv[i] = h;
        lv[i] = f2bf(v[i] - bf2f(h));
        s += v[i];
    }
    *(ushort4v*)(xh + (size_t)m * Kdim + k) = hv;
    *(ushort4v*)(xl + (size_t)m * Kdim + k) = lv;
#pragma unroll
    for (int off = 16; off > 0; off >>= 1) s += __shfl_down(s, off, 32);
    if (lane == 0) xsum[g * Mdim + m] = s;
}

// Main: 512 blocks = 256 n-tiles x 2 k-halves (kh in LSB -> per-XCD x locality).
// 512 threads = 8 waves = 4 m-tiles x 2 n-strips. q double-buffered in LDS,
// x single-buffered (52 KB total -> 2 blocks/CU). Writes fp32 partials.
__launch_bounds__(512, 4)
__global__ void qlin_kernel(const unsigned short* __restrict__ xh,
                            const unsigned short* __restrict__ xl,
                            const int* __restrict__ qw,
                            const float* __restrict__ scales,
                            const float* __restrict__ zeros,
                            const float* __restrict__ xsum,
                            float* __restrict__ pout) {
    __shared__ unsigned short lq[2][BN][PITCH];
    __shared__ unsigned short lxh[Mdim][PITCH];
    __shared__ unsigned short lxl[Mdim][PITCH];

    const int tid = threadIdx.x;
    const int kh = blockIdx.x & 1;
    const int n0 = (blockIdx.x >> 1) * BN;
    const int g0 = kh * NG2;
    const int w = tid >> 6;
    const int l = tid & 63;
    const int mt = w >> 1;        // m-tile 0..3 (16 rows each)
    const int wn = w & 1;         // n-strip 0..1 (16 cols each)
    const int lcol = l & 15;
    const int lhi = l >> 4;

    // q staging coords: thread covers 2 k-rows x 4 cols
    const int qc = tid & 7;       // col quad
    const int qp = tid >> 3;      // k-pair 0..63
    // x staging coords
    const int xm0 = tid >> 4;             // 0..31
    const int xk0 = (tid & 15) * 8;       // 0..120

    const int gn = n0 + wn * 16 + lcol;
    const int xsrow = mt * 16 + lhi * 4;

    int4v qa, qb;
    ushort8 ha0, ha1, la0, la1;
    float s_n, z_n;
    f32x4 xs_n;

    auto LOADS = [&](int g) {   // g absolute group index
        const size_t k0 = (size_t)g * GRP;
        qa = __builtin_nontemporal_load((const int4v*)(qw + (k0 + 2 * qp) * Ndim + n0 + 4 * qc));
        qb = __builtin_nontemporal_load((const int4v*)(qw + (k0 + 2 * qp + 1) * Ndim + n0 + 4 * qc));
        ha0 = *(const ushort8*)(xh + (size_t)xm0 * Kdim + k0 + xk0);
        ha1 = *(const ushort8*)(xh + (size_t)(xm0 + 32) * Kdim + k0 + xk0);
        la0 = *(const ushort8*)(xl + (size_t)xm0 * Kdim + k0 + xk0);
        la1 = *(const ushort8*)(xl + (size_t)(xm0 + 32) * Kdim + k0 + xk0);
        s_n = scales[(size_t)g * Ndim + gn];
        z_n = zeros[(size_t)g * Ndim + gn];
        xs_n = *(const f32x4*)(xsum + g * Mdim + xsrow);
    };
    auto WRITES = [&](int b) {
#pragma unroll
        for (int j = 0; j < 4; ++j) {
            unsigned int pk = (unsigned int)f2bf((float)qa[j]) |
                              ((unsigned int)f2bf((float)qb[j]) << 16);
            *(unsigned int*)&lq[b][4 * qc + j][2 * qp] = pk;
        }
        *(ushort8*)&lxh[xm0][xk0] = ha0;
        *(ushort8*)&lxh[xm0 + 32][xk0] = ha1;
        *(ushort8*)&lxl[xm0][xk0] = la0;
        *(ushort8*)&lxl[xm0 + 32][xk0] = la1;
    };

    f32x4 acc = {0.f, 0.f, 0.f, 0.f};
    f32x4 p = {0.f, 0.f, 0.f, 0.f};
    float s_c, z_c;
    f32x4 xs_c;

    LOADS(g0);
    WRITES(0);
    s_c = s_n; z_c = z_n; xs_c = xs_n;
    __syncthreads();

    for (int g = 0; g < NG2; ++g) {
        const int cb = g & 1;
        if (g + 1 < NG2) LOADS(g0 + g + 1);
#pragma unroll
        for (int ks = 0; ks < 4; ++ks) {
            short8 bfrag = *(const short8*)&lq[cb][wn * 16 + lcol][ks * 32 + lhi * 8];
            short8 ah = *(const short8*)&lxh[mt * 16 + lcol][ks * 32 + lhi * 8];
            short8 al = *(const short8*)&lxl[mt * 16 + lcol][ks * 32 + lhi * 8];
            p = __builtin_amdgcn_mfma_f32_16x16x32_bf16(ah, bfrag, p, 0, 0, 0);
            p = __builtin_amdgcn_mfma_f32_16x16x32_bf16(al, bfrag, p, 0, 0, 0);
        }
        // group epilogue in fp32 (regs only; s/z/xs were prefetched)
#pragma unroll
        for (int r = 0; r < 4; ++r) {
            acc[r] += s_c * (p[r] - z_c * xs_c[r]);
            p[r] = 0.f;
        }
        if (g + 1 < NG2) {
            __syncthreads();              // all reads of lxh/lxl done
            WRITES(cb ^ 1);
            s_c = s_n; z_c = z_n; xs_c = xs_n;
            __syncthreads();              // new tiles visible
        }
    }

#pragma unroll
    for (int r = 0; r < 4; ++r) {
        pout[(size_t)kh * Mdim * Ndim + (size_t)(mt * 16 + lhi * 4 + r) * Ndim + gn] = acc[r];
    }
}

// out = p0 + p1 + bias
__global__ void reduce_kernel(const float* __restrict__ pout,
                              const float* __restrict__ bias,
                              float* __restrict__ out) {
    const int i = blockIdx.x * 256 + threadIdx.x;   // f32x4 index
    const size_t e = (size_t)i * 4;
    const int n = (int)(e & (Ndim - 1));
    f32x4 a = *(const f32x4*)(pout + e);
    f32x4 b = *(const f32x4*)(pout + (size_t)Mdim * Ndim + e);
    f32x4 bv = *(const f32x4*)(bias + n);
    f32x4 o;
#pragma unroll
    for (int r = 0; r < 4; ++r) o[r] = a[r] + b[r] + bv[r];
    *(f32x4*)(out + e) = o;
}

extern "C" void kernel_launch(void* const* d_in, const int* in_sizes, int n_in,
                              void* d_out, int out_size, void* d_ws, size_t ws_size,
                              hipStream_t stream) {
    const float* x = (const float*)d_in[0];
    const int* qw = (const int*)d_in[1];
    const float* scales = (const float*)d_in[2];
    const float* zeros = (const float*)d_in[3];
    const float* bias = (const float*)d_in[4];

    unsigned short* xh = (unsigned short*)d_ws;
    unsigned short* xl = xh + (size_t)Mdim * Kdim;
    float* xsum = (float*)(xl + (size_t)Mdim * Kdim);
    float* pout = xsum + NGRP * Mdim;
    float* out = (float*)d_out;

    prep_kernel<<<512, 256, 0, stream>>>(x, xh, xl, xsum);
    qlin_kernel<<<Ndim / BN * KSPLIT, 512, 0, stream>>>(xh, xl, qw, scales, zeros, xsum, pout);
    reduce_kernel<<<(Mdim * Ndim / 4) / 256, 256, 0, stream>>>(pout, bias, out);
}